// Round 8
// baseline (338.130 us; speedup 1.0000x reference)
//
#include <hip/hip_runtime.h>
#include <math.h>

#define LMAX 8
#define NCOEF 45   // (LMAX+1)*(LMAX+2)/2

// Native clang vector type (HIP_vector_type float4 is a class).
typedef float f4 __attribute__((ext_vector_type(4)));

struct Coefs { float c[NCOEF]; };

#define PANEL 1024   // points per block (4 chunks of 256)
#define CHUNK 256    // points per chunk == blockDim

// Block-level LDS tile, reused by 4 flush groups:
//   group A: l=1..4, bases (floats) 0,768,2048,3840  -> 6144 floats
//   group B: l=5,6,  bases 0,2816                    -> 6144 floats
//   group C: l=7 base 0 (3840) ; group D: l=8 base 0 (4352)
// 6144 floats = 24 KB -> 6 blocks/CU (144 KB of 160 KB).
__global__ __launch_bounds__(256, 6) void sph_kernel(const float* __restrict__ R,
                                                     float* __restrict__ out,
                                                     int N, int nwg, Coefs cf) {
    __shared__ __align__(16) float tile[6144];

    // Bijective XCD-chunked swizzle (m204): same-XCD blocks own CONSECUTIVE
    // panels, so each XCD's L2 writes back 9 dense sequential fronts.
    const int bid = blockIdx.x;
    const int q = nwg >> 3, r = nwg & 7;
    const int xcd = bid & 7, idx = bid >> 3;
    const int swz = (xcd < r ? xcd * (q + 1) : r * (q + 1) + (xcd - r) * q) + idx;

    const int tid = threadIdx.x;
    const long long panel_base = (long long)swz * PANEL;

    const int TBASE[9] = {0, 0, 768, 2048, 3840, 0, 2816, 0, 0};

    for (int it = 0; it < PANEL / CHUNK; ++it) {
        const long long chunk0 = panel_base + (long long)it * CHUNK;
        int cnt = (int)((long long)N - chunk0);
        if (cnt <= 0) break;              // uniform across block
        if (cnt > CHUNK) cnt = CHUNK;

        const long long i = chunk0 + tid;
        float x = 0.0f, y = 0.0f, z = 1.0f;
        if (i < N) {
            x = R[3 * i + 0];
            y = R[3 * i + 1];
            z = R[3 * i + 2];
        }
        float rinv = 1.0f / sqrtf(x * x + y * y + z * z);
        x *= rinv; y *= rinv; z *= rinv;

        // l=0: constant, contiguous -> direct store, no LDS.
        if (i < N) out[i] = cf.c[0];

        // l-outer recurrence ladders, per-m state only.
        float A[LMAX + 1], B[LMAX + 1], P1[LMAX + 1], P2[LMAX + 1];
        A[0] = 1.0f; B[0] = 0.0f;
        P1[0] = 1.0f; P2[0] = 0.0f;

        #pragma unroll
        for (int l = 1; l <= LMAX; ++l) {
            A[l] = x * A[l - 1] - y * B[l - 1];
            B[l] = x * B[l - 1] + y * A[l - 1];

            const int w = 2 * l + 1;
            float* tw = tile + TBASE[l] + tid * w;   // odd stride: 2-way max (free)

            #pragma unroll
            for (int m = 0; m <= l; ++m) {
                float p;
                if (m == l) {
                    float pmm = 1.0f;                  // (2l-1)!! at compile time
                    #pragma unroll
                    for (int k = 1; k < 2 * l; k += 2) pmm *= (float)k;
                    p = pmm;
                    P2[m] = 0.0f;
                } else if (m == l - 1) {
                    p = (2.0f * (float)l - 1.0f) * z * P1[m];
                    P2[m] = P1[m];
                } else {
                    float o1 = P1[m];
                    p = ((2.0f * (float)l - 1.0f) * z * o1 - (float)(l + m - 1) * P2[m])
                        * (1.0f / (float)(l - m));     // folds to constant
                    P2[m] = o1;
                }
                P1[m] = p;
                float np = cf.c[l * (l + 1) / 2 + m] * p;
                if (m == 0) {
                    tw[l] = np;
                } else {
                    tw[l + m] = np * A[m];
                    tw[l - m] = np * B[m];
                }
            }

            // Block-cooperative flush at group boundaries: 256 threads write
            // one contiguous 256*w-float run per region (plain cached stores —
            // no nt — so L2 aggregates and writes back dense lines).
            const bool flush_now = (l == 4) || (l == 6) || (l == 7) || (l == 8);
            if (flush_now) {
                const int lo = (l == 4) ? 1 : (l == 6) ? 5 : l;
                __syncthreads();                       // writes visible to all waves
                #pragma unroll
                for (int fl = 1; fl <= LMAX; ++fl) {
                    if (fl < lo || fl > l) continue;   // folds away
                    const int fw = 2 * fl + 1;
                    const float* fs = tile + TBASE[fl];
                    const long long region = (long long)N * (long long)(fl * fl)
                                           + chunk0 * (long long)fw;
                    if (cnt == CHUNK && ((region & 3) == 0)) {
                        f4* __restrict__ out4 = (f4*)(out + region);
                        const f4* s4 = (const f4*)fs;
                        #pragma unroll
                        for (int t = tid; t < 64 * fw; t += 256)
                            out4[t] = s4[t];
                    } else {
                        for (int t = tid; t < cnt * fw; t += 256)
                            out[region + t] = fs[t];
                    }
                }
                __syncthreads();                       // reads done before reuse
            }
        }
    }
}

extern "C" void kernel_launch(void* const* d_in, const int* in_sizes, int n_in,
                              void* d_out, int out_size, void* d_ws, size_t ws_size,
                              hipStream_t stream) {
    const float* R = (const float*)d_in[0];
    float* out = (float*)d_out;
    int N = in_sizes[0] / 3;

    // Norms in l-outer order: idx = l*(l+1)/2 + m.
    Coefs cf;
    for (int l = 0; l <= LMAX; ++l) {
        for (int m = 0; m <= l; ++m) {
            double fr = 1.0;
            for (int k = l - m + 1; k <= l + m; ++k) fr *= (double)k;
            double norm = sqrt((double)(2 * l + 1) / (4.0 * M_PI) / fr);
            if (m > 0) norm *= sqrt(2.0);
            cf.c[l * (l + 1) / 2 + m] = (float)norm;
        }
    }

    int nwg = (N + PANEL - 1) / PANEL;
    sph_kernel<<<nwg, 256, 0, stream>>>(R, out, N, nwg, cf);
}

// Round 9
// 324.836 us; speedup vs baseline: 1.0409x; 1.0409x over previous
//
#include <hip/hip_runtime.h>
#include <math.h>

#define LMAX 8
#define NCOEF 45   // (LMAX+1)*(LMAX+2)/2
#define CHUNK 256  // points per block

// Native clang vector type (HIP_vector_type float4 is a class).
typedef float f4 __attribute__((ext_vector_type(4)));

struct Coefs { float c[NCOEF]; };

// One block computes ONE region l for CHUNK consecutive points and writes a
// single dense run of CHUNK*(2l+1) floats. Blocks are l-major, so the device
// writes region 0, then 1, ... then 8 as sequential fill-like fronts.
template<int L>
__device__ __forceinline__ void do_region(const float* __restrict__ R,
                                          float* __restrict__ out, int N,
                                          const Coefs& cf, int chunk, float* sm) {
    const int tid = threadIdx.x;
    const long long p0 = (long long)chunk * CHUNK;
    int cnt = (int)((long long)N - p0);
    if (cnt > CHUNK) cnt = CHUNK;                 // chunk < nchunks -> cnt > 0

    const long long i = p0 + tid;
    float x = 0.0f, y = 0.0f, z = 1.0f;
    if (i < N) { x = R[3 * i]; y = R[3 * i + 1]; z = R[3 * i + 2]; }
    float rinv = 1.0f / sqrtf(x * x + y * y + z * z);
    x *= rinv; y *= rinv; z *= rinv;

    constexpr int W = 2 * L + 1;
    const long long region = (long long)N * (L * L) + p0 * W;

    if (L == 0) {                                  // constant band: pure fill
        if (i < N) __builtin_nontemporal_store(cf.c[0], &out[i]);
        return;
    }

    // Band L only: A/B ladder to L, then P_L^m from P_m^m for each m.
    float Am[L + 1], Bm[L + 1];
    Am[0] = 1.0f; Bm[0] = 0.0f;
    #pragma unroll
    for (int m = 1; m <= L; ++m) {
        Am[m] = x * Am[m - 1] - y * Bm[m - 1];
        Bm[m] = x * Bm[m - 1] + y * Am[m - 1];
    }

    float vals[W];
    #pragma unroll
    for (int m = 0; m <= L; ++m) {
        float pmm = 1.0f;                          // (2m-1)!! at compile time
        #pragma unroll
        for (int k = 1; k < 2 * m; k += 2) pmm *= (float)k;
        float p1 = pmm, p2 = 0.0f, p = pmm;
        #pragma unroll
        for (int l = m + 1; l <= L; ++l) {
            p = (l == m + 1)
                ? (2.0f * (float)m + 1.0f) * z * p1
                : ((2.0f * (float)l - 1.0f) * z * p1 - (float)(l + m - 1) * p2)
                  * (1.0f / (float)(l - m));       // folds to constant
            p2 = p1; p1 = p;
        }
        float np = cf.c[L * (L + 1) / 2 + m] * p;
        if (m == 0) { vals[L] = np; }
        else { vals[L + m] = np * Am[m]; vals[L - m] = np * Bm[m]; }
    }

    // Stage 256 x W (odd stride -> bank-conflict-free), one barrier, then a
    // single contiguous nt flush (nt keeps L3 clean so input re-reads hit L3).
    #pragma unroll
    for (int c = 0; c < W; ++c) sm[tid * W + c] = vals[c];
    __syncthreads();

    if (cnt == CHUNK) {
        f4* __restrict__ out4 = (f4*)(out + region);   // region % 4 == 0 always
        const f4* s4 = (const f4*)sm;
        #pragma unroll
        for (int t = tid; t < CHUNK * W / 4; t += 256)
            __builtin_nontemporal_store(s4[t], &out4[t]);
    } else {
        for (int t = tid; t < cnt * W; t += 256)
            out[region + t] = sm[t];
    }
}

__global__ __launch_bounds__(256) void sph_kernel(const float* __restrict__ R,
                                                  float* __restrict__ out,
                                                  int N, int nchunks, Coefs cf) {
    __shared__ __align__(16) float sm[CHUNK * 17];
    const int l     = blockIdx.x / nchunks;    // l-major: one region at a time
    const int chunk = blockIdx.x % nchunks;    // device-wide dense write front
    switch (l) {
        case 0: do_region<0>(R, out, N, cf, chunk, sm); break;
        case 1: do_region<1>(R, out, N, cf, chunk, sm); break;
        case 2: do_region<2>(R, out, N, cf, chunk, sm); break;
        case 3: do_region<3>(R, out, N, cf, chunk, sm); break;
        case 4: do_region<4>(R, out, N, cf, chunk, sm); break;
        case 5: do_region<5>(R, out, N, cf, chunk, sm); break;
        case 6: do_region<6>(R, out, N, cf, chunk, sm); break;
        case 7: do_region<7>(R, out, N, cf, chunk, sm); break;
        case 8: do_region<8>(R, out, N, cf, chunk, sm); break;
    }
}

extern "C" void kernel_launch(void* const* d_in, const int* in_sizes, int n_in,
                              void* d_out, int out_size, void* d_ws, size_t ws_size,
                              hipStream_t stream) {
    const float* R = (const float*)d_in[0];
    float* out = (float*)d_out;
    int N = in_sizes[0] / 3;

    // Norms in l-outer order: idx = l*(l+1)/2 + m.
    Coefs cf;
    for (int l = 0; l <= LMAX; ++l) {
        for (int m = 0; m <= l; ++m) {
            double fr = 1.0;
            for (int k = l - m + 1; k <= l + m; ++k) fr *= (double)k;
            double norm = sqrt((double)(2 * l + 1) / (4.0 * M_PI) / fr);
            if (m > 0) norm *= sqrt(2.0);
            cf.c[l * (l + 1) / 2 + m] = (float)norm;
        }
    }

    int nchunks = (N + CHUNK - 1) / CHUNK;
    sph_kernel<<<9 * nchunks, 256, 0, stream>>>(R, out, N, nchunks, cf);
}